// Round 13
// baseline (213.977 us; speedup 1.0000x reference)
//
#include <hip/hip_runtime.h>
#include <hip/hip_bf16.h>

#define TROWS 1048576
#define RPC   256                    // rows per chunk
#define CPB   8                      // chunks per block
#define NBLK  (TROWS / (RPC * CPB))  // 512 blocks (2 per CU)
#define LSTRIDE 36                   // out0 LDS row stride in shorts (72 B)

typedef float f32x4  __attribute__((ext_vector_type(4)));
typedef short bf16x8 __attribute__((ext_vector_type(8)));
typedef short bf16x4 __attribute__((ext_vector_type(4)));

#define MFMA(a, b, c) __builtin_amdgcn_mfma_f32_16x16x32_bf16(a, b, c, 0, 0, 0)

__device__ __forceinline__ short f2bf(float v) {
    __hip_bfloat16 b = __float2bfloat16(v);
    return __builtin_bit_cast(short, b);
}
__device__ __forceinline__ float bf2f(short s) {
    unsigned u = ((unsigned)(unsigned short)s) << 16;
    return __builtin_bit_cast(float, u);
}

// k-map for ALL A/B fragments: kappa(g,j) = j<4 ? 4g+j : 16+4g+(j-4)
// ---------------------------------------------------------------------------
// Prep: weights -> bf16 fragment order (verified rounds 2-12).
//   W0a: frag 0..15 (ks*8+nt)   W0b: 16..23 (k2*2+ot)
//   W1a: 24..47 (ks*8+nt)       W1b: 48..55 (k2*2+ot)
// ---------------------------------------------------------------------------
__global__ __launch_bounds__(64) void prep_kernel(
    const float* __restrict__ W0a, const float* __restrict__ W0b,
    const float* __restrict__ W1a, const float* __restrict__ W1b,
    bf16x8* __restrict__ frag)
{
    const int fid = blockIdx.x, l = threadIdx.x, c = l & 15, g = l >> 4;
    const float* W; int N, ks, nt;
    if (fid < 16)      { W = W0a; N = 128; ks = fid >> 3;        nt = fid & 7; }
    else if (fid < 24) { W = W0b; N = 32;  ks = (fid - 16) >> 1; nt = (fid - 16) & 1; }
    else if (fid < 48) { W = W1a; N = 128; ks = (fid - 24) >> 3; nt = (fid - 24) & 7; }
    else               { W = W1b; N = 32;  ks = (fid - 48) >> 1; nt = (fid - 48) & 1; }
    bf16x8 f;
    #pragma unroll
    for (int j = 0; j < 8; ++j) {
        const int k = 32 * ks + ((j < 4) ? (4 * g + j) : (16 + 4 * g + (j - 4)));
        f[j] = f2bf(W[k * N + 16 * nt + c]);
    }
    frag[fid * 64 + l] = f;
}

// ---------------------------------------------------------------------------
// Persistent fused kernel: 512 blocks x 8 chunks x 256 rows. ALL 56 weight
// frags staged to LDS ONCE per block (no restaging, no W0/W1 union swap).
// Per chunk: convert prefetched x -> scan -> phase A -> B_mid -> prefetch
// next chunk (x/topk/wts, and wave3: p-update + x[p]) -> gather -> phase B
// -> blend/store -> B_end. p for chunk c+1 derives from chunk c's cummax.
// ---------------------------------------------------------------------------
__global__ __launch_bounds__(256, 2) void fused_kernel(
    const float* __restrict__ x, const int* __restrict__ topk,
    const float* __restrict__ wts,
    const float* __restrict__ b0a, const float* __restrict__ b0b,
    const float* __restrict__ b1a, const float* __restrict__ b1b,
    const bf16x8* __restrict__ frag,
    float* __restrict__ out)
{
    const int tid = threadIdx.x, wv = tid >> 6, l = tid & 63, c = l & 15, g = l >> 4;
    const int blk0 = blockIdx.x * (RPC * CPB);

    __shared__ __align__(16) short frag_lds[56 * 64 * 8];    // 57344 B, persistent
    __shared__ __align__(16) short out0_lds[257 * LSTRIDE];  // 18504 B
    __shared__ int wtot[4];

    #define LDSF(fid_) (*(const bf16x8*)&frag_lds[(((fid_) * 64) + l) * 8])

    // --- stage ALL 56 frags once: 14 x 16B per thread ---
    #pragma unroll
    for (int i = 0; i < 14; ++i)
        *(f32x4*)&frag_lds[(tid + i * 256) * 8] = *(const f32x4*)&frag[tid + i * 256];

    // --- wave 3: initial p (last mask0 row < blk0, input-only) + x[p] raw ---
    int p = 0; bool m0p = false;
    f32x4 xpraw[4];
    if (wv == 3) {
        for (int base = blk0 - 64; base >= 0; base -= 64) {
            const int2 tkq = ((const int2*)topk)[base + l];
            const bool mm = (tkq.x == 0) || (tkq.y == 0);
            const unsigned long long bal = __ballot(mm);
            if (bal) { p = base + 63 - __clzll(bal); break; }
        }
        const int2 tkp = ((const int2*)topk)[p];
        m0p = (tkp.x == 0) || (tkp.y == 0);
        const float* xp = x + (size_t)p * 64;
        xpraw[0] = *(const f32x4*)(xp + 4 * g);
        xpraw[1] = *(const f32x4*)(xp + 16 + 4 * g);
        xpraw[2] = *(const f32x4*)(xp + 32 + 4 * g);
        xpraw[3] = *(const f32x4*)(xp + 48 + 4 * g);
    }

    // --- chunk-0 inputs (x raw + topk + wts) ---
    f32x4 xraw[16];
    #pragma unroll
    for (int rt = 0; rt < 4; ++rt) {
        const float* xr = x + (size_t)(blk0 + wv * 64 + rt * 16 + c) * 64;
        xraw[rt * 4 + 0] = *(const f32x4*)(xr + 4 * g);
        xraw[rt * 4 + 1] = *(const f32x4*)(xr + 16 + 4 * g);
        xraw[rt * 4 + 2] = *(const f32x4*)(xr + 32 + 4 * g);
        xraw[rt * 4 + 3] = *(const f32x4*)(xr + 48 + 4 * g);
    }
    int2  tko = ((const int2*)topk)[blk0 + tid];
    float wgt = wts[(size_t)(blk0 + tid) * 2];

    __syncthreads();   // frags staged; safe to use LDSF from here on

    #pragma unroll 1
    for (int ch = 0; ch < CPB; ++ch) {
        const int cb = blk0 + ch * RPC;

        // --- convert raw x -> bf16 fragments ---
        bf16x8 xf[4][2];
        #pragma unroll
        for (int rt = 0; rt < 4; ++rt)
            #pragma unroll
            for (int ks = 0; ks < 2; ++ks) {
                const f32x4 a  = xraw[rt * 4 + ks * 2 + 0];
                const f32x4 b2 = xraw[rt * 4 + ks * 2 + 1];
                #pragma unroll
                for (int j = 0; j < 4; ++j) { xf[rt][ks][j] = f2bf(a[j]); xf[rt][ks][4 + j] = f2bf(b2[j]); }
            }
        bf16x8 xfp[2];
        if (wv == 3) {
            #pragma unroll
            for (int ks = 0; ks < 2; ++ks) {
                const f32x4 a  = xpraw[ks * 2 + 0];
                const f32x4 b2 = xpraw[ks * 2 + 1];
                #pragma unroll
                for (int j = 0; j < 4; ++j) { xfp[ks][j] = f2bf(a[j]); xfp[ks][4 + j] = f2bf(b2[j]); }
            }
        }

        // --- masks + wave-local cummax of (mask0 ? row : 0) ---
        const bool m0o = (tko.x == 0) || (tko.y == 0);
        const bool m1o = (tko.x == 1) || (tko.y == 1);
        const int  mo_own   = (m0o ? 1 : 0) | (m1o ? 2 : 0);
        const float wgt_own = wgt;
        int s = m0o ? (cb + tid) : 0;
        #pragma unroll
        for (int off = 1; off < 64; off <<= 1) {
            int u = __shfl_up(s, off, 64);
            if (l >= off) s = max(s, u);
        }
        if (l == 63) wtot[wv] = s;

        // ---- phase A: MLP0, k2-unrolled, frags from persistent LDS ----
        f32x4 acc2a[4][2], accp[2];
        {
            f32x4 bi0 = *(const f32x4*)(b0b + 4 * g);
            f32x4 bi1 = *(const f32x4*)(b0b + 16 + 4 * g);
            #pragma unroll
            for (int rt = 0; rt < 4; ++rt) { acc2a[rt][0] = bi0; acc2a[rt][1] = bi1; }
            accp[0] = bi0; accp[1] = bi1;
        }
        #pragma unroll
        for (int k2 = 0; k2 < 4; ++k2) {
            const bf16x8 fa00 = LDSF(0 * 8 + 2 * k2 + 0);
            const bf16x8 fa01 = LDSF(0 * 8 + 2 * k2 + 1);
            const bf16x8 fa10 = LDSF(1 * 8 + 2 * k2 + 0);
            const bf16x8 fa11 = LDSF(1 * 8 + 2 * k2 + 1);
            const bf16x8 fb0  = LDSF(16 + 2 * k2 + 0);
            const bf16x8 fb1  = LDSF(16 + 2 * k2 + 1);
            const f32x4 bi0 = *(const f32x4*)(b0a + 16 * (2 * k2 + 0) + 4 * g);
            const f32x4 bi1 = *(const f32x4*)(b0a + 16 * (2 * k2 + 1) + 4 * g);
            #pragma unroll
            for (int rt = 0; rt < 4; ++rt) {
                f32x4 a10 = bi0, a11 = bi1;
                a10 = MFMA(fa00, xf[rt][0], a10);
                a10 = MFMA(fa10, xf[rt][1], a10);
                a11 = MFMA(fa01, xf[rt][0], a11);
                a11 = MFMA(fa11, xf[rt][1], a11);
                bf16x8 hf;
                #pragma unroll
                for (int j = 0; j < 8; ++j)
                    hf[j] = f2bf(fmaxf((j < 4 ? a10 : a11)[j & 3], 0.0f));
                acc2a[rt][0] = MFMA(fb0, hf, acc2a[rt][0]);
                acc2a[rt][1] = MFMA(fb1, hf, acc2a[rt][1]);
            }
            if (wv == 3) {               // p-row tile shares this k2's frags
                f32x4 a10 = bi0, a11 = bi1;
                a10 = MFMA(fa00, xfp[0], a10);
                a10 = MFMA(fa10, xfp[1], a10);
                a11 = MFMA(fa01, xfp[0], a11);
                a11 = MFMA(fa11, xfp[1], a11);
                bf16x8 hf;
                #pragma unroll
                for (int j = 0; j < 8; ++j)
                    hf[j] = f2bf(fmaxf((j < 4 ? a10 : a11)[j & 3], 0.0f));
                accp[0] = MFMA(fb0, hf, accp[0]);
                accp[1] = MFMA(fb1, hf, accp[1]);
            }
        }

        // --- store own tiles (masked, shuffled mask) + p-tile slot 256 ---
        #pragma unroll
        for (int rt = 0; rt < 4; ++rt) {
            const int slot = wv * 64 + rt * 16 + c;
            const bool m0 = (__shfl(mo_own, rt * 16 + c, 64) & 1);
            #pragma unroll
            for (int ot = 0; ot < 2; ++ot) {
                bf16x4 v;
                #pragma unroll
                for (int j = 0; j < 4; ++j) v[j] = f2bf(m0 ? acc2a[rt][ot][j] : 0.0f);
                *(bf16x4*)(&out0_lds[slot * LSTRIDE + 16 * ot + 4 * g]) = v;
            }
        }
        if (wv == 3 && c == 0) {
            #pragma unroll
            for (int ot = 0; ot < 2; ++ot) {
                bf16x4 v;
                #pragma unroll
                for (int j = 0; j < 4; ++j) v[j] = f2bf(m0p ? accp[ot][j] : 0.0f);
                *(bf16x4*)(&out0_lds[256 * LSTRIDE + 16 * ot + 4 * g]) = v;
            }
        }

        __syncthreads();   // B_mid: out0 + wtot visible

        // --- prefetch next chunk inputs (land under phase B) ---
        if (ch + 1 < CPB) {
            const int nb = cb + RPC;
            #pragma unroll
            for (int rt = 0; rt < 4; ++rt) {
                const float* xr = x + (size_t)(nb + wv * 64 + rt * 16 + c) * 64;
                xraw[rt * 4 + 0] = *(const f32x4*)(xr + 4 * g);
                xraw[rt * 4 + 1] = *(const f32x4*)(xr + 16 + 4 * g);
                xraw[rt * 4 + 2] = *(const f32x4*)(xr + 32 + 4 * g);
                xraw[rt * 4 + 3] = *(const f32x4*)(xr + 48 + 4 * g);
            }
            tko = ((const int2*)topk)[nb + tid];
            wgt = wts[(size_t)(nb + tid) * 2];
        }

        // --- chunk-local prefix -> per-row global cummax ---
        int pre = 0;
        #pragma unroll
        for (int w2 = 0; w2 < 4; ++w2)
            if (w2 < wv) pre = max(pre, wtot[w2]);
        const int s_full = max(pre, s);

        // --- wave 3: p for next chunk = chunk cummax at last row (in-register) ---
        if (wv == 3 && ch + 1 < CPB) {
            const int sl = __shfl(s_full, 63, 64);
            if (sl > 0) { p = sl; m0p = true; }
            const float* xp = x + (size_t)p * 64;
            xpraw[0] = *(const f32x4*)(xp + 4 * g);
            xpraw[1] = *(const f32x4*)(xp + 16 + 4 * g);
            xpraw[2] = *(const f32x4*)(xp + 32 + 4 * g);
            xpraw[3] = *(const f32x4*)(xp + 48 + 4 * g);
        }

        // --- gather filled frags (slot 256 = p-tile when cummax < chunk base) ---
        bf16x8 xf2[4];
        #pragma unroll
        for (int rt = 0; rt < 4; ++rt) {
            const int sF = __shfl(s_full, rt * 16 + c, 64);
            const int slot = (sF >= cb) ? (sF - cb) : 256;
            const short* fr = &out0_lds[slot * LSTRIDE];
            bf16x4 fa_ = *(const bf16x4*)(fr + 4 * g);
            bf16x4 fb_ = *(const bf16x4*)(fr + 16 + 4 * g);
            #pragma unroll
            for (int j = 0; j < 4; ++j) { xf2[rt][j] = fa_[j]; xf2[rt][4 + j] = fb_[j]; }
        }

        // ---- phase B: MLP1, k2-unrolled ----
        f32x4 acc2b[4][2];
        {
            f32x4 bi0 = *(const f32x4*)(b1b + 4 * g);
            f32x4 bi1 = *(const f32x4*)(b1b + 16 + 4 * g);
            #pragma unroll
            for (int rt = 0; rt < 4; ++rt) { acc2b[rt][0] = bi0; acc2b[rt][1] = bi1; }
        }
        #pragma unroll
        for (int k2 = 0; k2 < 4; ++k2) {
            const bf16x8 fa00 = LDSF(24 + 0 * 8 + 2 * k2 + 0);
            const bf16x8 fa01 = LDSF(24 + 0 * 8 + 2 * k2 + 1);
            const bf16x8 fa10 = LDSF(24 + 1 * 8 + 2 * k2 + 0);
            const bf16x8 fa11 = LDSF(24 + 1 * 8 + 2 * k2 + 1);
            const bf16x8 fa20 = LDSF(24 + 2 * 8 + 2 * k2 + 0);
            const bf16x8 fa21 = LDSF(24 + 2 * 8 + 2 * k2 + 1);
            const bf16x8 fb0  = LDSF(48 + 2 * k2 + 0);
            const bf16x8 fb1  = LDSF(48 + 2 * k2 + 1);
            const f32x4 bi0 = *(const f32x4*)(b1a + 16 * (2 * k2 + 0) + 4 * g);
            const f32x4 bi1 = *(const f32x4*)(b1a + 16 * (2 * k2 + 1) + 4 * g);
            #pragma unroll
            for (int rt = 0; rt < 4; ++rt) {
                f32x4 a10 = bi0, a11 = bi1;
                a10 = MFMA(fa00, xf[rt][0], a10);
                a10 = MFMA(fa10, xf[rt][1], a10);
                a10 = MFMA(fa20, xf2[rt], a10);
                a11 = MFMA(fa01, xf[rt][0], a11);
                a11 = MFMA(fa11, xf[rt][1], a11);
                a11 = MFMA(fa21, xf2[rt], a11);
                bf16x8 hf;
                #pragma unroll
                for (int j = 0; j < 8; ++j)
                    hf[j] = f2bf(fmaxf((j < 4 ? a10 : a11)[j & 3], 0.0f));
                acc2b[rt][0] = MFMA(fb0, hf, acc2b[rt][0]);
                acc2b[rt][1] = MFMA(fb1, hf, acc2b[rt][1]);
            }
        }

        // --- blend + store ---
        #pragma unroll
        for (int rt = 0; rt < 4; ++rt) {
            const int slot = wv * 64 + rt * 16 + c;
            const int row = cb + slot;
            const int mo   = __shfl(mo_own, rt * 16 + c, 64);
            const float w  = __shfl(wgt_own, rt * 16 + c, 64);
            const float wc = 1.0f - w;
            const bool m1 = mo & 2;
            #pragma unroll
            for (int ot = 0; ot < 2; ++ot) {
                bf16x4 oa = *(const bf16x4*)(&out0_lds[slot * LSTRIDE + 16 * ot + 4 * g]);
                f32x4 r;
                #pragma unroll
                for (int j = 0; j < 4; ++j) {
                    const float e1 = m1 ? acc2b[rt][ot][j] : 0.0f;
                    r[j] = w * bf2f(oa[j]) + wc * e1;
                }
                *(f32x4*)(out + (size_t)row * 32 + 16 * ot + 4 * g) = r;
            }
        }

        __syncthreads();   // B_end: out0 reads done before next chunk overwrites
    }
    #undef LDSF
}

// ---------------------------------------------------------------------------
extern "C" void kernel_launch(void* const* d_in, const int* in_sizes, int n_in,
                              void* d_out, int out_size, void* d_ws, size_t ws_size,
                              hipStream_t stream)
{
    const float* x    = (const float*)d_in[0];
    const int*   topk = (const int*)  d_in[1];
    const float* wts  = (const float*)d_in[2];
    const float* W0a  = (const float*)d_in[3];
    const float* b0a  = (const float*)d_in[4];
    const float* W0b  = (const float*)d_in[5];
    const float* b0b  = (const float*)d_in[6];
    const float* W1a  = (const float*)d_in[7];
    const float* b1a  = (const float*)d_in[8];
    const float* W1b  = (const float*)d_in[9];
    const float* b1b  = (const float*)d_in[10];
    float* out = (float*)d_out;

    bf16x8* frag = (bf16x8*)d_ws;   // 56 KiB

    prep_kernel<<<dim3(56), dim3(64), 0, stream>>>(W0a, W0b, W1a, W1b, frag);
    fused_kernel<<<dim3(NBLK), dim3(256), 0, stream>>>(
        x, topk, wts, b0a, b0b, b1a, b1b, frag, out);
}

// Round 14
// 129.079 us; speedup vs baseline: 1.6577x; 1.6577x over previous
//
#include <hip/hip_runtime.h>
#include <hip/hip_bf16.h>

#define TROWS 1048576
#define RPC   256                    // rows per chunk
#define CPB   8                      // chunks per block
#define NBLK  (TROWS / (RPC * CPB))  // 512 blocks = 2 per CU
#define LSTRIDE 36                   // out0 LDS row stride in shorts (72 B)

typedef float f32x4  __attribute__((ext_vector_type(4)));
typedef short bf16x8 __attribute__((ext_vector_type(8)));
typedef short bf16x4 __attribute__((ext_vector_type(4)));

#define MFMA(a, b, c) __builtin_amdgcn_mfma_f32_16x16x32_bf16(a, b, c, 0, 0, 0)

__device__ __forceinline__ short f2bf(float v) {
    __hip_bfloat16 b = __float2bfloat16(v);
    return __builtin_bit_cast(short, b);
}
__device__ __forceinline__ float bf2f(short s) {
    unsigned u = ((unsigned)(unsigned short)s) << 16;
    return __builtin_bit_cast(float, u);
}

// k-map for ALL A/B fragments: kappa(g,j) = j<4 ? 4g+j : 16+4g+(j-4)
// ---------------------------------------------------------------------------
// Prep: weights -> bf16 fragment order (verified rounds 2-13).
//   W0a: frag 0..15 (ks*8+nt)   W0b: 16..23 (k2*2+ot)
//   W1a: 24..47 (ks*8+nt)       W1b: 48..55 (k2*2+ot)
// ---------------------------------------------------------------------------
__global__ __launch_bounds__(64) void prep_kernel(
    const float* __restrict__ W0a, const float* __restrict__ W0b,
    const float* __restrict__ W1a, const float* __restrict__ W1b,
    bf16x8* __restrict__ frag)
{
    const int fid = blockIdx.x, l = threadIdx.x, c = l & 15, g = l >> 4;
    const float* W; int N, ks, nt;
    if (fid < 16)      { W = W0a; N = 128; ks = fid >> 3;        nt = fid & 7; }
    else if (fid < 24) { W = W0b; N = 32;  ks = (fid - 16) >> 1; nt = (fid - 16) & 1; }
    else if (fid < 48) { W = W1a; N = 128; ks = (fid - 24) >> 3; nt = (fid - 24) & 7; }
    else               { W = W1b; N = 32;  ks = (fid - 48) >> 1; nt = (fid - 48) & 1; }
    bf16x8 f;
    #pragma unroll
    for (int j = 0; j < 8; ++j) {
        const int k = 32 * ks + ((j < 4) ? (4 * g + j) : (16 + 4 * g + (j - 4)));
        f[j] = f2bf(W[k * N + 16 * nt + c]);
    }
    frag[fid * 64 + l] = f;
}

// ---------------------------------------------------------------------------
// Persistent fused kernel: 512 blocks x 8 chunks x 256 rows. All 56 weight
// frags staged once (no restage). Per chunk: convert prefetched x -> scan ->
// phase A -> stores -> B_mid -> prefetch next x (raw regs) -> gather ->
// phase B -> blend/store -> p-tile reg-bounce -> B_end. p-tile for chunk n+1
// is COPIED from chunk n's out0 table (cummax row), not recomputed.
// ---------------------------------------------------------------------------
__global__ __launch_bounds__(256, 2) void fused_kernel(
    const float* __restrict__ x, const int* __restrict__ topk,
    const float* __restrict__ wts,
    const float* __restrict__ b0a, const float* __restrict__ b0b,
    const float* __restrict__ b1a, const float* __restrict__ b1b,
    const bf16x8* __restrict__ frag,
    float* __restrict__ out)
{
    const int tid = threadIdx.x, wv = tid >> 6, l = tid & 63, c = l & 15, g = l >> 4;
    const int blk0 = blockIdx.x * (RPC * CPB);

    __shared__ __align__(16) short frag_lds[56 * 64 * 8];    // 57344 B persistent
    __shared__ __align__(16) short out0_lds[257 * LSTRIDE];  // 18504 B
    __shared__ int wtot[4];

    #define LDSF(fid_) (*(const bf16x8*)&frag_lds[(((fid_) * 64) + l) * 8])

    // --- stage ALL 56 frags once: 14 x 16B per thread ---
    #pragma unroll
    for (int i = 0; i < 14; ++i)
        *(f32x4*)&frag_lds[(tid + i * 256) * 8] = *(const f32x4*)&frag[tid + i * 256];

    // --- wave 3: initial p (last mask0 row < blk0) + x[p] -> bf16 frags ---
    bf16x8 xfp[2];
    bool m0p = false;
    if (wv == 3) {
        int p = 0;
        for (int base = blk0 - 64; base >= 0; base -= 64) {
            const int2 tkq = ((const int2*)topk)[base + l];
            const bool mm = (tkq.x == 0) || (tkq.y == 0);
            const unsigned long long bal = __ballot(mm);
            if (bal) { p = base + 63 - __clzll(bal); break; }
        }
        const int2 tkp = ((const int2*)topk)[p];
        m0p = (tkp.x == 0) || (tkp.y == 0);
        const float* xp = x + (size_t)p * 64;
        #pragma unroll
        for (int ks = 0; ks < 2; ++ks) {
            f32x4 a  = *(const f32x4*)(xp + 32 * ks + 4 * g);
            f32x4 b2 = *(const f32x4*)(xp + 32 * ks + 16 + 4 * g);
            #pragma unroll
            for (int j = 0; j < 4; ++j) { xfp[ks][j] = f2bf(a[j]); xfp[ks][4 + j] = f2bf(b2[j]); }
        }
    }

    // --- chunk-0 inputs ---
    f32x4 xraw[16];
    #pragma unroll
    for (int rt = 0; rt < 4; ++rt) {
        const float* xr = x + (size_t)(blk0 + wv * 64 + rt * 16 + c) * 64;
        xraw[rt * 4 + 0] = *(const f32x4*)(xr + 4 * g);
        xraw[rt * 4 + 1] = *(const f32x4*)(xr + 16 + 4 * g);
        xraw[rt * 4 + 2] = *(const f32x4*)(xr + 32 + 4 * g);
        xraw[rt * 4 + 3] = *(const f32x4*)(xr + 48 + 4 * g);
    }
    int2  tko = ((const int2*)topk)[blk0 + tid];
    float wgt = wts[(size_t)(blk0 + tid) * 2];

    __syncthreads();   // frags staged

    // --- wave 3: initial p-tile via MLP0 -> slot 256 (once per block) ---
    if (wv == 3) {
        f32x4 accp0 = *(const f32x4*)(b0b + 4 * g);
        f32x4 accp1 = *(const f32x4*)(b0b + 16 + 4 * g);
        #pragma unroll 1
        for (int k2 = 0; k2 < 4; ++k2) {
            const bf16x8 fa00 = LDSF(0 * 8 + 2 * k2 + 0);
            const bf16x8 fa01 = LDSF(0 * 8 + 2 * k2 + 1);
            const bf16x8 fa10 = LDSF(1 * 8 + 2 * k2 + 0);
            const bf16x8 fa11 = LDSF(1 * 8 + 2 * k2 + 1);
            const bf16x8 fb0  = LDSF(16 + 2 * k2 + 0);
            const bf16x8 fb1  = LDSF(16 + 2 * k2 + 1);
            f32x4 a10 = *(const f32x4*)(b0a + 16 * (2 * k2 + 0) + 4 * g);
            f32x4 a11 = *(const f32x4*)(b0a + 16 * (2 * k2 + 1) + 4 * g);
            a10 = MFMA(fa00, xfp[0], a10);
            a10 = MFMA(fa10, xfp[1], a10);
            a11 = MFMA(fa01, xfp[0], a11);
            a11 = MFMA(fa11, xfp[1], a11);
            bf16x8 hf;
            #pragma unroll
            for (int j = 0; j < 8; ++j)
                hf[j] = f2bf(fmaxf((j < 4 ? a10 : a11)[j & 3], 0.0f));
            accp0 = MFMA(fb0, hf, accp0);
            accp1 = MFMA(fb1, hf, accp1);
        }
        if (c == 0) {
            #pragma unroll
            for (int ot = 0; ot < 2; ++ot) {
                bf16x4 v;
                #pragma unroll
                for (int j = 0; j < 4; ++j)
                    v[j] = f2bf(m0p ? (ot ? accp1[j] : accp0[j]) : 0.0f);
                *(bf16x4*)(&out0_lds[256 * LSTRIDE + 16 * ot + 4 * g]) = v;
            }
        }
    }
    // slot 256 is complete before any gather (gathers are post-B_mid).

    #pragma unroll 1
    for (int ch = 0; ch < CPB; ++ch) {
        const int cb = blk0 + ch * RPC;

        // --- convert raw x -> bf16 fragments (loads landed during prev phase B) ---
        bf16x8 xf[4][2];
        #pragma unroll
        for (int rt = 0; rt < 4; ++rt)
            #pragma unroll
            for (int ks = 0; ks < 2; ++ks) {
                const f32x4 a  = xraw[rt * 4 + ks * 2 + 0];
                const f32x4 b2 = xraw[rt * 4 + ks * 2 + 1];
                #pragma unroll
                for (int j = 0; j < 4; ++j) { xf[rt][ks][j] = f2bf(a[j]); xf[rt][ks][4 + j] = f2bf(b2[j]); }
            }

        // --- wave-local cummax of (mask0 ? row : 0) ---
        const bool m0o = (tko.x == 0) || (tko.y == 0);
        int s = m0o ? (cb + tid) : 0;
        #pragma unroll
        for (int off = 1; off < 64; off <<= 1) {
            int u = __shfl_up(s, off, 64);
            if (l >= off) s = max(s, u);
        }
        if (l == 63) wtot[wv] = s;

        // ---- phase A: MLP0, rolled k2, frags from persistent LDS ----
        f32x4 acc2a[4][2];
        {
            f32x4 bi0 = *(const f32x4*)(b0b + 4 * g);
            f32x4 bi1 = *(const f32x4*)(b0b + 16 + 4 * g);
            #pragma unroll
            for (int rt = 0; rt < 4; ++rt) { acc2a[rt][0] = bi0; acc2a[rt][1] = bi1; }
        }
        #pragma unroll 1
        for (int k2 = 0; k2 < 4; ++k2) {
            const bf16x8 fa00 = LDSF(0 * 8 + 2 * k2 + 0);
            const bf16x8 fa01 = LDSF(0 * 8 + 2 * k2 + 1);
            const bf16x8 fa10 = LDSF(1 * 8 + 2 * k2 + 0);
            const bf16x8 fa11 = LDSF(1 * 8 + 2 * k2 + 1);
            const bf16x8 fb0  = LDSF(16 + 2 * k2 + 0);
            const bf16x8 fb1  = LDSF(16 + 2 * k2 + 1);
            const f32x4 bi0 = *(const f32x4*)(b0a + 16 * (2 * k2 + 0) + 4 * g);
            const f32x4 bi1 = *(const f32x4*)(b0a + 16 * (2 * k2 + 1) + 4 * g);
            #pragma unroll
            for (int rt = 0; rt < 4; ++rt) {
                f32x4 a10 = bi0, a11 = bi1;
                a10 = MFMA(fa00, xf[rt][0], a10);
                a10 = MFMA(fa10, xf[rt][1], a10);
                a11 = MFMA(fa01, xf[rt][0], a11);
                a11 = MFMA(fa11, xf[rt][1], a11);
                bf16x8 hf;
                #pragma unroll
                for (int j = 0; j < 8; ++j)
                    hf[j] = f2bf(fmaxf((j < 4 ? a10 : a11)[j & 3], 0.0f));
                acc2a[rt][0] = MFMA(fb0, hf, acc2a[rt][0]);
                acc2a[rt][1] = MFMA(fb1, hf, acc2a[rt][1]);
            }
        }

        // --- store own tiles (masked, direct topk read) ---
        #pragma unroll
        for (int rt = 0; rt < 4; ++rt) {
            const int slot = wv * 64 + rt * 16 + c;
            const int2 tk = ((const int2*)topk)[cb + slot];
            const bool m0 = (tk.x == 0) || (tk.y == 0);
            #pragma unroll
            for (int ot = 0; ot < 2; ++ot) {
                bf16x4 v;
                #pragma unroll
                for (int j = 0; j < 4; ++j) v[j] = f2bf(m0 ? acc2a[rt][ot][j] : 0.0f);
                *(bf16x4*)(&out0_lds[slot * LSTRIDE + 16 * ot + 4 * g]) = v;
            }
        }

        __syncthreads();   // B_mid: out0 + wtot + slot 256 visible

        // --- prefetch next chunk inputs (issue now; land under phase B) ---
        if (ch + 1 < CPB) {
            const int nb = cb + RPC;
            #pragma unroll
            for (int rt = 0; rt < 4; ++rt) {
                const float* xr = x + (size_t)(nb + wv * 64 + rt * 16 + c) * 64;
                xraw[rt * 4 + 0] = *(const f32x4*)(xr + 4 * g);
                xraw[rt * 4 + 1] = *(const f32x4*)(xr + 16 + 4 * g);
                xraw[rt * 4 + 2] = *(const f32x4*)(xr + 32 + 4 * g);
                xraw[rt * 4 + 3] = *(const f32x4*)(xr + 48 + 4 * g);
            }
            tko = ((const int2*)topk)[nb + tid];
            wgt = wts[(size_t)(nb + tid) * 2];
        }

        // --- chunk prefix -> global cummax per row ---
        int pre = 0;
        #pragma unroll
        for (int w2 = 0; w2 < 4; ++w2)
            if (w2 < wv) pre = max(pre, wtot[w2]);
        const int s_full = max(pre, s);

        // --- gather filled frags (slot 256 = p-tile when cummax < chunk base) ---
        bf16x8 xf2[4];
        #pragma unroll
        for (int rt = 0; rt < 4; ++rt) {
            const int sF = __shfl(s_full, rt * 16 + c, 64);
            const int slot = (sF >= cb) ? (sF - cb) : 256;
            const short* fr = &out0_lds[slot * LSTRIDE];
            bf16x4 fa_ = *(const bf16x4*)(fr + 4 * g);
            bf16x4 fb_ = *(const bf16x4*)(fr + 16 + 4 * g);
            #pragma unroll
            for (int j = 0; j < 4; ++j) { xf2[rt][j] = fa_[j]; xf2[rt][4 + j] = fb_[j]; }
        }

        // ---- phase B: MLP1, rolled k2 ----
        f32x4 acc2b[4][2];
        {
            f32x4 bi0 = *(const f32x4*)(b1b + 4 * g);
            f32x4 bi1 = *(const f32x4*)(b1b + 16 + 4 * g);
            #pragma unroll
            for (int rt = 0; rt < 4; ++rt) { acc2b[rt][0] = bi0; acc2b[rt][1] = bi1; }
        }
        #pragma unroll 1
        for (int k2 = 0; k2 < 4; ++k2) {
            const bf16x8 fa00 = LDSF(24 + 0 * 8 + 2 * k2 + 0);
            const bf16x8 fa01 = LDSF(24 + 0 * 8 + 2 * k2 + 1);
            const bf16x8 fa10 = LDSF(24 + 1 * 8 + 2 * k2 + 0);
            const bf16x8 fa11 = LDSF(24 + 1 * 8 + 2 * k2 + 1);
            const bf16x8 fa20 = LDSF(24 + 2 * 8 + 2 * k2 + 0);
            const bf16x8 fa21 = LDSF(24 + 2 * 8 + 2 * k2 + 1);
            const bf16x8 fb0  = LDSF(48 + 2 * k2 + 0);
            const bf16x8 fb1  = LDSF(48 + 2 * k2 + 1);
            const f32x4 bi0 = *(const f32x4*)(b1a + 16 * (2 * k2 + 0) + 4 * g);
            const f32x4 bi1 = *(const f32x4*)(b1a + 16 * (2 * k2 + 1) + 4 * g);
            #pragma unroll
            for (int rt = 0; rt < 4; ++rt) {
                f32x4 a10 = bi0, a11 = bi1;
                a10 = MFMA(fa00, xf[rt][0], a10);
                a10 = MFMA(fa10, xf[rt][1], a10);
                a10 = MFMA(fa20, xf2[rt], a10);
                a11 = MFMA(fa01, xf[rt][0], a11);
                a11 = MFMA(fa11, xf[rt][1], a11);
                a11 = MFMA(fa21, xf2[rt], a11);
                bf16x8 hf;
                #pragma unroll
                for (int j = 0; j < 8; ++j)
                    hf[j] = f2bf(fmaxf((j < 4 ? a10 : a11)[j & 3], 0.0f));
                acc2b[rt][0] = MFMA(fb0, hf, acc2b[rt][0]);
                acc2b[rt][1] = MFMA(fb1, hf, acc2b[rt][1]);
            }
        }

        // --- blend + store (direct topk/wts reads, r7-proven) ---
        #pragma unroll
        for (int rt = 0; rt < 4; ++rt) {
            const int slot = wv * 64 + rt * 16 + c;
            const int row = cb + slot;
            const int2 tk = ((const int2*)topk)[row];
            const bool m1 = (tk.x == 1) || (tk.y == 1);
            const float w  = wts[(size_t)row * 2];
            const float wc = 1.0f - w;
            #pragma unroll
            for (int ot = 0; ot < 2; ++ot) {
                bf16x4 oa = *(const bf16x4*)(&out0_lds[slot * LSTRIDE + 16 * ot + 4 * g]);
                f32x4 r;
                #pragma unroll
                for (int j = 0; j < 4; ++j) {
                    const float e1 = m1 ? acc2b[rt][ot][j] : 0.0f;
                    r[j] = w * bf2f(oa[j]) + wc * e1;
                }
                *(f32x4*)(out + (size_t)row * 32 + 16 * ot + 4 * g) = r;
            }
        }

        // --- p-tile refresh: wave 3 bounces the cummax row through 2 regs ---
        uint2 pc; bool docopy = false;
        if (ch + 1 < CPB && wv == 3) {
            const int pn = __shfl(s_full, 63, 64);   // global cummax at row cb+255
            docopy = (pn >= cb);
            if (docopy && l < 8)
                pc = *(const uint2*)&out0_lds[(pn - cb) * LSTRIDE + l * 4];
        }

        __syncthreads();   // B_end: all out0 reads of this chunk done

        if (docopy && l < 8)
            *(uint2*)&out0_lds[256 * LSTRIDE + l * 4] = pc;
        // (write visible to all at next B_mid; slots 0..255 stores are disjoint)
    }
    #undef LDSF
}

// ---------------------------------------------------------------------------
extern "C" void kernel_launch(void* const* d_in, const int* in_sizes, int n_in,
                              void* d_out, int out_size, void* d_ws, size_t ws_size,
                              hipStream_t stream)
{
    const float* x    = (const float*)d_in[0];
    const int*   topk = (const int*)  d_in[1];
    const float* wts  = (const float*)d_in[2];
    const float* W0a  = (const float*)d_in[3];
    const float* b0a  = (const float*)d_in[4];
    const float* W0b  = (const float*)d_in[5];
    const float* b0b  = (const float*)d_in[6];
    const float* W1a  = (const float*)d_in[7];
    const float* b1a  = (const float*)d_in[8];
    const float* W1b  = (const float*)d_in[9];
    const float* b1b  = (const float*)d_in[10];
    float* out = (float*)d_out;

    bf16x8* frag = (bf16x8*)d_ws;   // 56 KiB

    prep_kernel<<<dim3(56), dim3(64), 0, stream>>>(W0a, W0b, W1a, W1b, frag);
    fused_kernel<<<dim3(NBLK), dim3(256), 0, stream>>>(
        x, topk, wts, b0a, b0b, b1a, b1b, frag, out);
}